// Round 1
// baseline (97.017 us; speedup 1.0000x reference)
//
#include <hip/hip_runtime.h>

// Problem constants (match reference)
#define BB 8
#define NN 512
#define NUM_GT 64
#define CC 16
#define FH 16
#define FW 16

// Output layout (floats):
//   label_map: [B*N][C][FH][FW]  -> 4096*4096 = 16777216
//   offset:    [B*N][4][FH][FW]  -> 4096*1024 =  4194304
//   mask:      [B*N][C]          -> 4096*16   =    65536
#define LM_FLOATS (BB*NN*CC*FH*FW)        // 16777216
#define OFF_FLOATS (BB*NN*4*FH*FW)        // 4194304

__global__ __launch_bounds__(256) void rcnn_encode_kernel(
    const float* __restrict__ boxes,          // (B,N,4)
    const float* __restrict__ gt_boxes,       // (B,NUM_GT,5)
    const int*   __restrict__ match_pos_flag, // (B,N)
    const int*   __restrict__ match_gt_id,    // (B,N)
    float* __restrict__ out)
{
    const int bn  = blockIdx.x;          // 0..B*N-1
    const int b   = bn >> 9;             // bn / N  (N=512)
    const int tid = threadIdx.x;         // 0..255

    __shared__ __align__(16) float heat_lds[FH*FW];   // 256 floats

    // ---- per-(b,n) scalars (computed redundantly; loads broadcast) ----
    const float bx1 = boxes[bn*4+0];
    const float by1 = boxes[bn*4+1];
    const float bx2 = boxes[bn*4+2];
    const float by2 = boxes[bn*4+3];

    const int gid  = match_gt_id[bn];
    const int gidc = min(max(gid, 0), NUM_GT-1);       // clamp like reference
    const float* g = gt_boxes + (size_t)(b*NUM_GT + gidc)*5;
    const float gx1 = g[0], gy1 = g[1], gx2 = g[2], gy2 = g[3], label = g[4];
    const int flag = match_pos_flag[bn];

    // zoom boxes by (1.1, 1.1)
    const float cx = (bx1 + bx2) * 0.5f;
    const float cy = (by1 + by2) * 0.5f;
    const float zw = (bx2 - bx1) * 1.1f;
    const float zh = (by2 - by1) * 1.1f;
    const float ax1 = cx - zw * 0.5f;
    const float ay1 = cy - zh * 0.5f;
    const float ax2 = cx + zw * 0.5f;
    const float ay2 = cy + zh * 0.5f;

    const float rx1 = gx1 - ax1;
    const float ry1 = gy1 - ay1;
    const float rx2 = gx2 - ax1;
    const float ry2 = gy2 - ay1;
    const float rw  = rx2 - rx1;
    const float rh  = ry2 - ry1;
    const float rcx = (rx1 + rx2) * 0.5f;
    const float rcy = (ry1 + ry2) * 0.5f;
    const float sw  = (ax2 - ax1) / 16.0f;   // /FW, exact pow2 scale
    const float sh  = (ay2 - ay1) / 16.0f;

    const float w_sigma = (rw * 0.5f) / sw;  // rw/2/sw
    const float h_sigma = (rh * 0.5f) / sh;
    const float w_sig_s = fmaxf(w_sigma, 1.5f);
    const float h_sig_s = fmaxf(h_sigma, 1.5f);
    const float w_sig_c = fmaxf(w_sigma, 0.5f);
    const float h_sig_c = fmaxf(h_sigma, 0.5f);
    const float pos_w = rcx / sw;
    const float pos_h = rcy / sh;
    const bool  small = (sw < 0.01f) || (sh < 0.01f);

    // offset plane values (per-axis)
    const float ox1v = rx1 / sw;
    const float oy1v = ry1 / sh;
    const float ox2v = rx2 / sw;
    const float oy2v = ry2 / sh;

    // ---- heat for this thread's (h,w); tid = h*16 + w ----
    {
        const float fw_ = (float)(tid & 15);
        const float fh_ = (float)(tid >> 4);
        const float wt = ((pos_w - fw_) - 0.5f) / w_sig_s;
        const float ht = ((pos_h - fh_) - 0.5f) / h_sig_s;
        const float heat = expf(-(wt*wt + ht*ht));
        const bool cond = (fabsf((fw_ + 0.5f) - pos_w) < w_sig_c) &&
                          (fabsf((fh_ + 0.5f) - pos_h) < h_sig_c);
        heat_lds[tid] = (cond && !small) ? heat : 0.0f;
    }
    __syncthreads();

    const float c_match = fabsf(label) - 1.0f;   // float compare like reference

    // ---- label_map: 4096 floats per bn = 1024 float4; 4 per thread ----
    {
        float4* lm = (float4*)out + (size_t)bn * 1024;
        const float4* heat4 = (const float4*)heat_lds;
        #pragma unroll
        for (int k = 0; k < 4; ++k) {
            const int f = k*256 + tid;           // float4 idx in [0,1024)
            const int c = f >> 6;                // channel (wave-uniform)
            float4 v = make_float4(0.f, 0.f, 0.f, 0.f);
            if ((float)c == c_match) {
                v = heat4[f & 63];               // 4 consecutive positions
            }
            lm[f] = v;
        }
    }

    // ---- offset: 1024 floats per bn = 256 float4; 1 per thread ----
    {
        float4* of = (float4*)(out + (size_t)LM_FLOATS) + (size_t)bn * 256;
        const int comp  = tid >> 6;              // 0..3 (wave-uniform)
        const int pbase = (tid & 63) << 2;       // 4 consecutive positions
        float4 v;
        #pragma unroll
        for (int j = 0; j < 4; ++j) {
            const int p = pbase + j;
            const float fw_ = (float)(p & 15);
            const float fh_ = (float)(p >> 4);
            float val;
            if      (comp == 0) val = ox1v - (fw_ + 0.5f);
            else if (comp == 1) val = oy1v - (fh_ + 0.5f);
            else if (comp == 2) val = ox2v - (fw_ + 0.5f);
            else                val = oy2v - (fh_ + 0.5f);
            ((float*)&v)[j] = small ? 0.0f : val;
        }
        of[tid] = v;
    }

    // ---- mask: 16 floats per bn ----
    if (tid < CC) {
        const bool pos_match = flag > 0;
        const float nnl = (flag != 0) ? label : 0.0f;   // non_neg_label
        const bool mask_one = pos_match && (nnl > 0.0f); // CLS_ON_HARD=False
        const bool m = ((float)tid == c_match) && mask_one;
        out[(size_t)LM_FLOATS + (size_t)OFF_FLOATS + (size_t)bn*CC + tid] = m ? 1.0f : 0.0f;
    }
}

extern "C" void kernel_launch(void* const* d_in, const int* in_sizes, int n_in,
                              void* d_out, int out_size, void* d_ws, size_t ws_size,
                              hipStream_t stream) {
    const float* boxes          = (const float*)d_in[0];
    const float* gt_boxes       = (const float*)d_in[1];
    const int*   match_pos_flag = (const int*)d_in[2];
    const int*   match_gt_id    = (const int*)d_in[3];
    float* out = (float*)d_out;

    rcnn_encode_kernel<<<BB*NN, 256, 0, stream>>>(
        boxes, gt_boxes, match_pos_flag, match_gt_id, out);
}